// Round 1
// baseline (345.911 us; speedup 1.0000x reference)
//
#include <hip/hip_runtime.h>

// Persistent LSTM: N=4096, T=256, IN=2, E=64, H=128, OUT=2.
// 256 blocks x 512 threads (8 waves). Block b owns batch rows [16b, 16b+16).
// Per step: gates[16,512] = [embed|h][16,192] @ B[192,512] via MFMA 16x16x32 bf16.
// Wave w owns gate columns permuted as (gate t, unit 16w+s) so each lane keeps
// all 4 gates of its (row, unit) pairs in registers -> elementwise is LDS-free.
// c state lives in registers; h/embed ping-pong through a small LDS A-buffer.

#define T_LEN 256
#define E_DIM 64
#define H_DIM 128
#define ROWS  16
#define NT    4     // n-tiles per wave == gates i,f,g,o
#define KT    6     // k-tiles: 2 embed (64) + 4 hidden (128)
#define ASTR  200   // A-buffer row stride (bf16 elems): 400B row -> 2-way bank alias (free), 16B aligned

typedef __attribute__((ext_vector_type(8))) short short8;
typedef __attribute__((ext_vector_type(4))) float f32x4;

__device__ __forceinline__ unsigned short f2bf(float f) {
  unsigned u = __builtin_bit_cast(unsigned, f);
  u += 0x7fffu + ((u >> 16) & 1u);           // RNE
  return (unsigned short)(u >> 16);
}
__device__ __forceinline__ float bf2f(unsigned short h) {
  unsigned u = ((unsigned)h) << 16;
  return __builtin_bit_cast(float, u);
}
__device__ __forceinline__ float sigf(float x) {
  float e = __builtin_amdgcn_exp2f(x * -1.442695041f);
  return __builtin_amdgcn_rcpf(1.0f + e);    // x->-inf: e->inf, rcp(inf)=0 OK
}
__device__ __forceinline__ float tanh_f(float x) {
  float ax = __builtin_fabsf(x);
  float e  = __builtin_amdgcn_exp2f(ax * -2.885390082f);
  float r  = (1.0f - e) * __builtin_amdgcn_rcpf(1.0f + e);
  return __builtin_copysignf(r, x);
}

__global__ __launch_bounds__(512, 2) void lstm_persist(
    const float* __restrict__ x,    const float* __restrict__ W_in,
    const float* __restrict__ b_in, const float* __restrict__ W_ih,
    const float* __restrict__ W_hh, const float* __restrict__ b_ih,
    const float* __restrict__ b_hh, const float* __restrict__ W_out,
    const float* __restrict__ b_out, float* __restrict__ out)
{
  __shared__ __align__(16) float xs[ROWS][2 * T_LEN];          // 32 KB: all x for this block
  __shared__ __align__(16) unsigned short Abuf[2][ROWS][ASTR]; // ping-pong [embed|h] bf16
  __shared__ float WinS[E_DIM * 2];
  __shared__ float binS[E_DIM];
  __shared__ float WoutS[2 * H_DIM];
  __shared__ float boutS[2];

  const int tid  = threadIdx.x;
  const int w    = tid >> 6;       // wave 0..7
  const int l    = tid & 63;
  const int l15  = l & 15;
  const int lq   = l >> 4;         // 0..3
  const int u    = w * 16 + l15;   // hidden unit 0..127 owned by this lane
  const int row0 = lq * 4;         // first of 4 C-rows this lane holds

  // ---------------- prologue: stage x + small weights ----------------
  const float* xg = x + (size_t)blockIdx.x * ROWS * 2 * T_LEN;
  for (int i = tid; i < ROWS * 2 * T_LEN / 4; i += 512)
    ((float4*)&xs[0][0])[i] = ((const float4*)xg)[i];
  if (tid < E_DIM * 2) WinS[tid]  = W_in[tid];
  if (tid < E_DIM)     binS[tid]  = b_in[tid];
  if (tid < 2 * H_DIM) WoutS[tid] = W_out[tid];
  if (tid < 2)         boutS[tid] = b_out[tid];

  // ---------------- weights -> per-wave B fragments (registers, bf16) ----------------
  // B[k][n]: k<64 -> W_ih[grow][k], k>=64 -> W_hh[grow][k-64]; column n of tile t = gate t, unit u.
  short8 fb[NT][KT];
  float  bias[NT];
  #pragma unroll
  for (int t = 0; t < NT; ++t) {
    const int grow = t * H_DIM + u;          // PyTorch gate order i,f,g,o
    bias[t] = b_ih[grow] + b_hh[grow];
    #pragma unroll
    for (int kt = 0; kt < KT; ++kt) {
      const int kk = kt * 32 + lq * 8;
      const float* src = (kk < E_DIM) ? (W_ih + grow * E_DIM + kk)
                                      : (W_hh + grow * H_DIM + (kk - E_DIM));
      float4 lo = *(const float4*)src;
      float4 hi = *(const float4*)(src + 4);
      short8 f;
      f[0] = (short)f2bf(lo.x); f[1] = (short)f2bf(lo.y);
      f[2] = (short)f2bf(lo.z); f[3] = (short)f2bf(lo.w);
      f[4] = (short)f2bf(hi.x); f[5] = (short)f2bf(hi.y);
      f[6] = (short)f2bf(hi.z); f[7] = (short)f2bf(hi.w);
      fb[t][kt] = f;
    }
  }

  __syncthreads();   // xs ready (embed0 reads it)

  // h0 = 0 in buffer 0
  for (int i = tid; i < ROWS * H_DIM; i += 512)
    Abuf[0][i >> 7][E_DIM + (i & 127)] = 0;
  // embed0 into buffer 0
  {
    const int r = tid >> 5;
    const float x0 = xs[r][0], x1 = xs[r][1];
    #pragma unroll
    for (int s = 0; s < 2; ++s) {
      const int e = (tid & 31) + s * 32;
      float v = fmaf(x1, WinS[e * 2 + 1], fmaf(x0, WinS[e * 2], binS[e]));
      Abuf[0][r][e] = f2bf(v > 0.f ? v : 0.f);
    }
  }
  __syncthreads();

  // ---------------- main recurrence ----------------
  float c[4] = {0.f, 0.f, 0.f, 0.f};
  const size_t out_base = (size_t)blockIdx.x * ROWS * 2 * T_LEN;
  const int pr = tid >> 5;         // y-proj: row
  const int po = (tid >> 4) & 1;   // y-proj: output channel
  const int pl = tid & 15;         // y-proj: 16-lane reduction group

  for (int t = 0; t < T_LEN; ++t) {
    const int p = t & 1;
    unsigned short (*bufR)[ASTR] = Abuf[p];
    unsigned short (*bufW)[ASTR] = Abuf[p ^ 1];

    f32x4 acc[NT];
    #pragma unroll
    for (int n = 0; n < NT; ++n)
      acc[n] = (f32x4){bias[n], bias[n], bias[n], bias[n]};

    #pragma unroll
    for (int kt = 0; kt < KT; ++kt) {
      const short8 a = *(const short8*)&bufR[l15][kt * 32 + lq * 8];
      #pragma unroll
      for (int n = 0; n < NT; ++n)
        acc[n] = __builtin_amdgcn_mfma_f32_16x16x32_bf16(a, fb[n][kt], acc[n], 0, 0, 0);
    }

    // elementwise LSTM cell (all in registers) + h_{t+1} -> write buffer
    #pragma unroll
    for (int q = 0; q < 4; ++q) {
      const float ig = sigf(acc[0][q]);
      const float fg = sigf(acc[1][q]);
      const float gg = tanh_f(acc[2][q]);
      const float og = sigf(acc[3][q]);
      const float cn = fmaf(fg, c[q], ig * gg);
      c[q] = cn;
      const float hn = og * tanh_f(cn);
      bufW[row0 + q][E_DIM + u] = f2bf(hn);
    }

    // embed_{t+1} -> write buffer
    if (t + 1 < T_LEN) {
      const float x0 = xs[pr][2 * (t + 1)], x1 = xs[pr][2 * (t + 1) + 1];
      #pragma unroll
      for (int s = 0; s < 2; ++s) {
        const int e = (tid & 31) + s * 32;
        float v = fmaf(x1, WinS[e * 2 + 1], fmaf(x0, WinS[e * 2], binS[e]));
        bufW[pr][e] = f2bf(v > 0.f ? v : 0.f);
      }
    }

    __syncthreads();   // the ONE barrier per step: write-buffer now complete

    // y_t = h_{t+1} @ W_out^T + b_out + x_t
    {
      const short8 hv = *(const short8*)&bufW[pr][E_DIM + pl * 8];
      float s = 0.f;
      #pragma unroll
      for (int e = 0; e < 8; ++e)
        s = fmaf(bf2f((unsigned short)hv[e]), WoutS[po * H_DIM + pl * 8 + e], s);
      s += __shfl_xor(s, 1);
      s += __shfl_xor(s, 2);
      s += __shfl_xor(s, 4);
      s += __shfl_xor(s, 8);
      if (pl == 0)
        out[out_base + (size_t)pr * 2 * T_LEN + 2 * t + po] = s + boutS[po] + xs[pr][2 * t + po];
    }
  }
}

extern "C" void kernel_launch(void* const* d_in, const int* in_sizes, int n_in,
                              void* d_out, int out_size, void* d_ws, size_t ws_size,
                              hipStream_t stream) {
  const float* x     = (const float*)d_in[0];
  const float* W_in  = (const float*)d_in[1];
  const float* b_in  = (const float*)d_in[2];
  const float* W_ih  = (const float*)d_in[3];
  const float* W_hh  = (const float*)d_in[4];
  const float* b_ih  = (const float*)d_in[5];
  const float* b_hh  = (const float*)d_in[6];
  const float* W_out = (const float*)d_in[7];
  const float* b_out = (const float*)d_in[8];
  float* out = (float*)d_out;

  lstm_persist<<<dim3(256), dim3(512), 0, stream>>>(
      x, W_in, b_in, W_ih, W_hh, b_ih, b_hh, W_out, b_out, out);
}

// Round 2
// 262.788 us; speedup vs baseline: 1.3163x; 1.3163x over previous
//
#include <hip/hip_runtime.h>

// Persistent LSTM: N=4096, T=256, IN=2, E=64, H=128, OUT=2.
// 256 blocks x 512 threads (8 waves), block b owns rows [16b,16b+16).
// Gates [16,512] = [embed|h][16,192] @ B[192,512] via mfma_f32_16x16x32_bf16.
// Wave w owns gate columns (gate t, unit 16w+l15) -> elementwise is register-local.
// 3 rotating A-buffers: embed written 2 steps ahead => next step's embed-part
// MFMAs (kt 0..1) are pre-issued BEFORE the barrier (fills matrix-pipe drain).
// y-projection is 4 extra MFMA tiles on wave 0 (lagged one step) + epilogue.

#define T_LEN 256
#define ROWS  16
#define NT    4
#define KT    6
#define ASTR  200

typedef __attribute__((ext_vector_type(8))) short short8;
typedef __attribute__((ext_vector_type(4))) float f32x4;
typedef __attribute__((ext_vector_type(2))) float f32x2;

__device__ __forceinline__ unsigned short f2bf(float f) {
  unsigned u = __builtin_bit_cast(unsigned, f);
  u += 0x7fffu + ((u >> 16) & 1u);           // RNE
  return (unsigned short)(u >> 16);
}
__device__ __forceinline__ f32x2 exp2v(f32x2 x) {
  return (f32x2){__builtin_amdgcn_exp2f(x[0]), __builtin_amdgcn_exp2f(x[1])};
}
__device__ __forceinline__ f32x2 rcpv(f32x2 x) {
  return (f32x2){__builtin_amdgcn_rcpf(x[0]), __builtin_amdgcn_rcpf(x[1])};
}

// fused LSTM cell on a pair of rows: sigmoid/tanh with shared rcp's.
// sig(x)=1/(1+2^(K1 x)), tanh(x)=(1-2^(K2 x))/(1+2^(K2 x)), K1=-log2e, K2=-2log2e
__device__ __forceinline__ f32x2 ewpair(f32x2 i, f32x2 f, f32x2 g, f32x2 o, f32x2& c) {
  const float K1 = -1.4426950408889634f, K2 = -2.8853900817779268f;
  f32x2 ei = exp2v(i * K1);
  f32x2 ef = exp2v(f * K1);
  f32x2 eg = exp2v(g * K2);
  f32x2 eo = exp2v(o * K1);
  f32x2 t1 = ei + 1.f, tf = ef + 1.f, t2 = eg + 1.f, t3 = 1.f - eg, to = eo + 1.f;
  f32x2 q1 = t1 * t2;
  f32x2 num = c * q1 + t3 * tf;      // c*(1+ei)(1+eg) + (1-eg)(1+ef)
  f32x2 cn = num * rcpv(q1 * tf);
  c = cn;
  f32x2 cc = __builtin_elementwise_min(
      __builtin_elementwise_max(cn, (f32x2){-20.f, -20.f}), (f32x2){20.f, 20.f});
  f32x2 ec = exp2v(cc * K2);
  return (1.f - ec) * rcpv(to * (ec + 1.f));   // sig(o)*tanh(c')
}

__global__ __launch_bounds__(512, 2) void lstm_persist(
    const float* __restrict__ x,    const float* __restrict__ W_in,
    const float* __restrict__ b_in, const float* __restrict__ W_ih,
    const float* __restrict__ W_hh, const float* __restrict__ b_ih,
    const float* __restrict__ b_hh, const float* __restrict__ W_out,
    const float* __restrict__ b_out, float* __restrict__ out)
{
  __shared__ __align__(16) float xsT[2 * T_LEN][ROWS];           // transposed x: 32 KB
  __shared__ __align__(16) unsigned short Abuf[3][ROWS][ASTR];   // rotating [embed|h]
  __shared__ float WinS[128];
  __shared__ float binS[64];

  const int tid  = threadIdx.x;
  const int w    = tid >> 6;
  const int l    = tid & 63;
  const int l15  = l & 15;
  const int lq   = l >> 4;
  const int u    = w * 16 + l15;
  const int row0 = lq * 4;

  // ---- stage x transposed (broadcast-friendly reads later) ----
  const float* xg = x + (size_t)blockIdx.x * ROWS * 2 * T_LEN;
  for (int i = tid; i < ROWS * 2 * T_LEN / 4; i += 512) {
    float4 v = ((const float4*)xg)[i];
    int fi = i * 4, r = fi >> 9, c0 = fi & 511;
    xsT[c0][r] = v.x; xsT[c0 + 1][r] = v.y; xsT[c0 + 2][r] = v.z; xsT[c0 + 3][r] = v.w;
  }
  if (tid < 128) WinS[tid] = W_in[tid];
  if (tid < 64)  binS[tid] = b_in[tid];

  // ---- gate weights -> per-wave B fragments ----
  short8 fb[NT][KT];
  f32x4  biasv[NT];
  #pragma unroll
  for (int t = 0; t < NT; ++t) {
    const int grow = t * 128 + u;
    const float bv = b_ih[grow] + b_hh[grow];
    biasv[t] = (f32x4){bv, bv, bv, bv};
    #pragma unroll
    for (int kt = 0; kt < KT; ++kt) {
      const int kk = kt * 32 + lq * 8;
      const float* src = (kk < 64) ? (W_ih + grow * 64 + kk)
                                   : (W_hh + grow * 128 + (kk - 64));
      float4 lo = *(const float4*)src;
      float4 hi = *(const float4*)(src + 4);
      short8 f;
      f[0] = (short)f2bf(lo.x); f[1] = (short)f2bf(lo.y);
      f[2] = (short)f2bf(lo.z); f[3] = (short)f2bf(lo.w);
      f[4] = (short)f2bf(hi.x); f[5] = (short)f2bf(hi.y);
      f[6] = (short)f2bf(hi.z); f[7] = (short)f2bf(hi.w);
      fb[t][kt] = f;
    }
  }
  // y-projection B fragments (cols 0,1 = W_out rows; rest zero), k = h-part only
  short8 fbY[4];
  #pragma unroll
  for (int kt = 0; kt < 4; ++kt) {
    short8 fy = {0, 0, 0, 0, 0, 0, 0, 0};
    if (l15 < 2) {
      const float* src = W_out + l15 * 128 + kt * 32 + lq * 8;
      #pragma unroll
      for (int j = 0; j < 8; ++j) fy[j] = (short)f2bf(src[j]);
    }
    fbY[kt] = fy;
  }
  const float bout_r = (l15 < 2) ? b_out[l15] : 0.f;

  __syncthreads();

  auto embed_to = [&](unsigned short (*buf)[ASTR], int t) {
    const int r = tid >> 5;
    const float x0 = xsT[2 * t][r], x1 = xsT[2 * t + 1][r];
    #pragma unroll
    for (int s = 0; s < 2; ++s) {
      const int e = (tid & 31) + s * 32;
      float v = fmaf(x1, WinS[2 * e + 1], fmaf(x0, WinS[2 * e], binS[e]));
      buf[r][e] = f2bf(v > 0.f ? v : 0.f);
    }
  };

  // h0 = 0 in buf0; embeds e0 -> buf0, e1 -> buf1
  for (int i = tid; i < ROWS * 128; i += 512)
    Abuf[0][i >> 7][64 + (i & 127)] = 0;
  embed_to(Abuf[0], 0);
  embed_to(Abuf[1], 1);
  __syncthreads();

  // seed accA with bias + embed-part MFMAs for t=0
  f32x4 accA[NT], accB[NT];
  {
    const short8 a0 = *(const short8*)&Abuf[0][l15][lq * 8];
    const short8 a1 = *(const short8*)&Abuf[0][l15][32 + lq * 8];
    #pragma unroll
    for (int n = 0; n < NT; ++n) {
      f32x4 acc = biasv[n];
      acc = __builtin_amdgcn_mfma_f32_16x16x32_bf16(a0, fb[n][0], acc, 0, 0, 0);
      acc = __builtin_amdgcn_mfma_f32_16x16x32_bf16(a1, fb[n][1], acc, 0, 0, 0);
      accA[n] = acc;
    }
  }

  f32x2 c01 = {0.f, 0.f}, c23 = {0.f, 0.f};
  const size_t obase = (size_t)blockIdx.x * ROWS * 2 * T_LEN;

  auto step = [&](int t, unsigned short (*bR)[ASTR], unsigned short (*bW)[ASTR],
                  unsigned short (*bE)[ASTR], f32x4 (&accC)[NT], f32x4 (&accN)[NT]) {
    // h-part fragments + 16 gate MFMAs
    short8 ah[4];
    #pragma unroll
    for (int kt = 0; kt < 4; ++kt)
      ah[kt] = *(const short8*)&bR[l15][(kt + 2) * 32 + lq * 8];
    #pragma unroll
    for (int kt = 0; kt < 4; ++kt) {
      #pragma unroll
      for (int n = 0; n < NT; ++n)
        accC[n] = __builtin_amdgcn_mfma_f32_16x16x32_bf16(ah[kt], fb[n][kt + 2], accC[n], 0, 0, 0);
    }

    // y_{t-1} = h_t @ W_out^T + b_out + x_{t-1}  (wave 0, 4 extra MFMAs)
    f32x4 accY;
    if (w == 0) {
      const int tt = (t > 0) ? t - 1 : 0;
      #pragma unroll
      for (int q = 0; q < 4; ++q)
        accY[q] = (l15 < 2) ? (bout_r + xsT[2 * tt + l15][row0 + q]) : 0.f;
      #pragma unroll
      for (int kt = 0; kt < 4; ++kt)
        accY = __builtin_amdgcn_mfma_f32_16x16x32_bf16(ah[kt], fbY[kt], accY, 0, 0, 0);
    }

    // pre-issue next step's embed-part MFMAs (e_{t+1} resident in bW since t-1)
    if (t + 1 < T_LEN) {
      const short8 a0 = *(const short8*)&bW[l15][lq * 8];
      const short8 a1 = *(const short8*)&bW[l15][32 + lq * 8];
      #pragma unroll
      for (int n = 0; n < NT; ++n) {
        f32x4 acc = biasv[n];
        acc = __builtin_amdgcn_mfma_f32_16x16x32_bf16(a0, fb[n][0], acc, 0, 0, 0);
        acc = __builtin_amdgcn_mfma_f32_16x16x32_bf16(a1, fb[n][1], acc, 0, 0, 0);
        accN[n] = acc;
      }
    }

    // elementwise (fused-exp, packed pairs) -> h_{t+1} into bW
    {
      f32x2 i01 = {accC[0][0], accC[0][1]}, f01 = {accC[1][0], accC[1][1]};
      f32x2 g01 = {accC[2][0], accC[2][1]}, o01 = {accC[3][0], accC[3][1]};
      f32x2 h01 = ewpair(i01, f01, g01, o01, c01);
      bW[row0 + 0][64 + u] = f2bf(h01[0]);
      bW[row0 + 1][64 + u] = f2bf(h01[1]);
      f32x2 i23 = {accC[0][2], accC[0][3]}, f23 = {accC[1][2], accC[1][3]};
      f32x2 g23 = {accC[2][2], accC[2][3]}, o23 = {accC[3][2], accC[3][3]};
      f32x2 h23 = ewpair(i23, f23, g23, o23, c23);
      bW[row0 + 2][64 + u] = f2bf(h23[0]);
      bW[row0 + 3][64 + u] = f2bf(h23[1]);
    }

    // embed e_{t+2} -> bE
    if (t + 2 < T_LEN) embed_to(bE, t + 2);

    // write y_{t-1}
    if (w == 0 && t > 0 && l15 < 2) {
      #pragma unroll
      for (int q = 0; q < 4; ++q)
        out[obase + (size_t)(row0 + q) * (2 * T_LEN) + 2 * (t - 1) + l15] = accY[q];
    }

    __syncthreads();
  };

  unsigned short (*B0)[ASTR] = Abuf[0];
  unsigned short (*B1)[ASTR] = Abuf[1];
  unsigned short (*B2)[ASTR] = Abuf[2];

  for (int t = 0; t < 252; t += 6) {
    step(t + 0, B0, B1, B2, accA, accB);
    step(t + 1, B1, B2, B0, accB, accA);
    step(t + 2, B2, B0, B1, accA, accB);
    step(t + 3, B0, B1, B2, accB, accA);
    step(t + 4, B1, B2, B0, accA, accB);
    step(t + 5, B2, B0, B1, accB, accA);
  }
  step(252, B0, B1, B2, accA, accB);
  step(253, B1, B2, B0, accB, accA);
  step(254, B2, B0, B1, accA, accB);
  step(255, B0, B1, B2, accB, accA);

  // epilogue: y_{T-1} = h_T @ W_out^T + b_out + x_{T-1}; h_T is in Abuf[1]
  if (w == 0) {
    short8 ah[4];
    #pragma unroll
    for (int kt = 0; kt < 4; ++kt)
      ah[kt] = *(const short8*)&Abuf[1][l15][(kt + 2) * 32 + lq * 8];
    f32x4 accY;
    #pragma unroll
    for (int q = 0; q < 4; ++q)
      accY[q] = (l15 < 2) ? (bout_r + xsT[2 * 255 + l15][row0 + q]) : 0.f;
    #pragma unroll
    for (int kt = 0; kt < 4; ++kt)
      accY = __builtin_amdgcn_mfma_f32_16x16x32_bf16(ah[kt], fbY[kt], accY, 0, 0, 0);
    if (l15 < 2) {
      #pragma unroll
      for (int q = 0; q < 4; ++q)
        out[obase + (size_t)(row0 + q) * (2 * T_LEN) + 2 * 255 + l15] = accY[q];
    }
  }
}

extern "C" void kernel_launch(void* const* d_in, const int* in_sizes, int n_in,
                              void* d_out, int out_size, void* d_ws, size_t ws_size,
                              hipStream_t stream) {
  const float* x     = (const float*)d_in[0];
  const float* W_in  = (const float*)d_in[1];
  const float* b_in  = (const float*)d_in[2];
  const float* W_ih  = (const float*)d_in[3];
  const float* W_hh  = (const float*)d_in[4];
  const float* b_ih  = (const float*)d_in[5];
  const float* b_hh  = (const float*)d_in[6];
  const float* W_out = (const float*)d_in[7];
  const float* b_out = (const float*)d_in[8];
  float* out = (float*)d_out;

  lstm_persist<<<dim3(256), dim3(512), 0, stream>>>(
      x, W_in, b_in, W_ih, W_hh, b_ih, b_hh, W_out, b_out, out);
}